// Round 3
// baseline (407.761 us; speedup 1.0000x reference)
//
#include <hip/hip_runtime.h>
#include <hip/hip_bf16.h>
#include <math.h>

typedef short bf16x8 __attribute__((ext_vector_type(8)));
typedef short bf16x4 __attribute__((ext_vector_type(4)));
typedef float f32x4 __attribute__((ext_vector_type(4)));

#define NSEQ 2048
#define DMODEL 2048
#define NH 16
#define HD 128
#define BATCH 2
#define MROWS 4096  // BATCH*NSEQ

__device__ __forceinline__ unsigned short f2b(float f) {
    __hip_bfloat16 h = __float2bfloat16(f);
    return *reinterpret_cast<unsigned short*>(&h);
}
__device__ __forceinline__ float b2f(unsigned short u) {
    __hip_bfloat16 h;
    *reinterpret_cast<unsigned short*>(&h) = u;
    return __bfloat162float(h);
}

__device__ __forceinline__ void gld_lds16(const unsigned short* g, unsigned short* l) {
    __builtin_amdgcn_global_load_lds(
        (const __attribute__((address_space(1))) unsigned int*)(const void*)g,
        (__attribute__((address_space(3))) unsigned int*)(void*)l,
        16, 0, 0);
}

// ---------------- fused cast fp32 -> bf16 for x + 4 weights (HBM-roofline) ----------------
__global__ __launch_bounds__(256) void cast_all_kernel(const float* __restrict__ x,
                                                       const float* __restrict__ wq,
                                                       const float* __restrict__ wk,
                                                       const float* __restrict__ wv,
                                                       const float* __restrict__ wo,
                                                       unsigned short* __restrict__ xb,
                                                       unsigned short* __restrict__ wqb) {
    int bid = blockIdx.x;
    const float* src;
    unsigned short* dst;
    int off;
    if (bid < 4096) {
        src = x; dst = xb; off = bid;
    } else {
        int w = (bid - 4096) >> 11;
        src = (w == 0) ? wq : (w == 1) ? wk : (w == 2) ? wv : wo;
        dst = wqb + (size_t)w * 4194304;
        off = (bid - 4096) & 2047;
    }
    int i = (off * 256 + threadIdx.x) * 8;
    float4 a = *(const float4*)(src + i);
    float4 b = *(const float4*)(src + i + 4);
    union { unsigned short u[8]; uint4 v; } tmp;
    tmp.u[0] = f2b(a.x); tmp.u[1] = f2b(a.y); tmp.u[2] = f2b(a.z); tmp.u[3] = f2b(a.w);
    tmp.u[4] = f2b(b.x); tmp.u[5] = f2b(b.y); tmp.u[6] = f2b(b.z); tmp.u[7] = f2b(b.w);
    *(uint4*)(dst + i) = tmp.v;
}

// ---------------- QKV GEMM + fused RoPE: 128x384 tile, K=32 slice ring (depth 4) ----------------
// Grid 32x16 = 512 blocks = EXACTLY 2 rounds of 256 CUs (round-1 lesson: 384 blocks
// = 1.5 rounds ate the schedule's gain). One s_barrier per slice; counted vmcnt(8)
// steady-state (never 0 until tail). 8 waves (2M x 4N), per-wave 64x96 output,
// acc[4][6]. LDS 128 KiB = 4 slots x (sA 8KB + sB 24KB). Both-sides XOR chunk
// swizzle (measured 0 conflicts in round 1). XCD-bijective grid, m-fastest within
// an n-column: the 32 resident blocks/XCD share one 1.5MB B-panel (L2-resident).
// Wave n-cols interleaved by 64 so RoPE (d, d+64) pairs are wave-local; heads are
// 128-aligned so a head never crosses the Q/K/V region boundary.
__global__ __launch_bounds__(512, 2) void gemm_qkv(const unsigned short* __restrict__ A,
                                                   const unsigned short* __restrict__ Bw,
                                                   unsigned short* __restrict__ qk,
                                                   unsigned short* __restrict__ vt) {
    __shared__ unsigned short sA[4][128 * 32];
    __shared__ unsigned short sB[4][384 * 32];
    const int K = DMODEL;
    const int tid = threadIdx.x;
    const int wave = tid >> 6, lane = tid & 63;

    const int bid = blockIdx.x;
    const int xcd = bid & 7, cc_ = bid >> 3;          // 64 tiles per XCD
    const int m0 = (cc_ & 31) * 128;                  // m-fastest
    const int n0 = (xcd * 2 + (cc_ >> 5)) * 384;      // 2 n-columns per XCD

    const int wr = wave >> 2, wc = wave & 3;
    const int fr = lane & 15, grp = lane >> 4;
    const int rsw = (grp ^ ((fr >> 1) & 3)) << 3;     // swizzled k-chunk for ds_read

    // staging: one 128-row sweep per gld_lds: row = base + wave*16 + (lane>>2),
    // LDS chunk = lane&3 (linear dest), fetched global chunk = (lane&3)^((row>>1)&3).
    const int sr = wave * 16 + (lane >> 2);
    const int sc = (((lane & 3) ^ ((lane >> 3) & 3)) << 3);
    const unsigned short* Ag = A + (size_t)(m0 + sr) * K + sc;
    const unsigned short* Bg = Bw + (size_t)(n0 + sr) * K + sc;

    f32x4 acc[4][6] = {};

    #define QKV_STAGE(sl, t)                                                          \
        {                                                                             \
            gld_lds16(Ag + (t) * 32, &sA[sl][(wave * 16) * 32]);                      \
            gld_lds16(Bg + (t) * 32, &sB[sl][(wave * 16) * 32]);                      \
            gld_lds16(Bg + (size_t)128 * K + (t) * 32, &sB[sl][(128 + wave * 16) * 32]); \
            gld_lds16(Bg + (size_t)256 * K + (t) * 32, &sB[sl][(256 + wave * 16) * 32]); \
        }

    // prologue: stage slices 0..2 (12 loads), wait for slice 0 (oldest 4) -> vmcnt(8)
    QKV_STAGE(0, 0);
    QKV_STAGE(1, 1);
    QKV_STAGE(2, 2);
    __builtin_amdgcn_sched_barrier(0);
    asm volatile("s_waitcnt vmcnt(8)" ::: "memory");
    asm volatile("s_barrier" ::: "memory");

    const int aoff = (wr * 64 + fr) * 32 + rsw;   // + mt*512
    const int boff = (wc * 16 + fr) * 32 + rsw;   // + nt*2048

    for (int s = 0; s < 64; s++) {
        const int slot = s & 3;
        // stage slice s+3 into slot (s+3)&3 == (s-1)&3 (vacated at the s-1 barrier)
        if (s < 61) { QKV_STAGE((s + 3) & 3, s + 3); }

        bf16x8 af[4], bfr[6];
        #pragma unroll
        for (int mt = 0; mt < 4; mt++)
            af[mt] = *(const bf16x8*)&sA[slot][aoff + mt * 512];
        #pragma unroll
        for (int nt = 0; nt < 6; nt++)
            bfr[nt] = *(const bf16x8*)&sB[slot][boff + nt * 2048];

        __builtin_amdgcn_sched_barrier(0);
        asm volatile("s_waitcnt lgkmcnt(0)" ::: "memory");
        __builtin_amdgcn_sched_barrier(0);
        __builtin_amdgcn_s_setprio(1);
        #pragma unroll
        for (int mt = 0; mt < 4; mt++)
            #pragma unroll
            for (int nt = 0; nt < 6; nt++)
                acc[mt][nt] = __builtin_amdgcn_mfma_f32_16x16x32_bf16(af[mt], bfr[nt], acc[mt][nt], 0, 0, 0);
        __builtin_amdgcn_s_setprio(0);
        __builtin_amdgcn_sched_barrier(0);
        // counted drain: slice s+1's 4 loads must be landed before next slice reads.
        if (s < 61)       { asm volatile("s_waitcnt vmcnt(8)" ::: "memory"); }
        else if (s == 61) { asm volatile("s_waitcnt vmcnt(4)" ::: "memory"); }
        else if (s == 62) { asm volatile("s_waitcnt vmcnt(0)" ::: "memory"); }
        asm volatile("s_barrier" ::: "memory");
    }
    #undef QKV_STAGE

    // ---------- epilogue ----------
    // acc[mt][nt][r]: row = m0 + wr*64 + mt*16 + grp*4 + r,
    //                 col = n0 + wc*16 + c0 + nt*64   (nt pairs (2p,2p+1) = RoPE lo/hi)
    const int g4 = grp * 4, c0 = fr;
    const int colb = n0 + wc * 16 + c0;
    if (n0 < 4096) {
        // RoPE region present. Angle depends only on (row, wc*16+c0) -> sincos once/row.
        const float inv = exp2f((float)(wc * 16 + c0) * -0.2076205059304545f);  // 10000^(-d/64)
        #pragma unroll
        for (int mt = 0; mt < 4; mt++) {
            #pragma unroll
            for (int r = 0; r < 4; r++) {
                int row = m0 + wr * 64 + mt * 16 + g4 + r;
                float nf = (float)(row & (NSEQ - 1));
                float sv, cv;
                __sincosf(nf * inv, &sv, &cv);
                size_t rb = (size_t)row * 2048;
                #pragma unroll
                for (int p = 0; p < 3; p++) {
                    int collo = colb + p * 128;
                    if (collo < 4096) {
                        int region = collo >> 11;   // 0=Q, 1=K
                        float scale = (region == 0) ? 0.08838834764831845f : 1.0f;
                        unsigned short* dst = qk + (size_t)region * 8388608 + (collo & 2047);
                        float lo = acc[mt][2 * p][r], hi = acc[mt][2 * p + 1][r];
                        dst[rb]      = f2b((lo * cv - hi * sv) * scale);
                        dst[rb + 64] = f2b((hi * cv + lo * sv) * scale);
                    }
                }
            }
        }
    }
    if (n0 + 383 >= 4096) {
        // V region present: store transposed [b][d][seq], uint2 over 4 seq rows.
        #pragma unroll
        for (int p = 0; p < 3; p++) {
            int collo = colb + p * 128;
            if (collo >= 4096) {
                #pragma unroll
                for (int j = 0; j < 2; j++) {
                    int d = collo + j * 64 - 4096;
                    #pragma unroll
                    for (int mt = 0; mt < 4; mt++) {
                        int row0 = m0 + wr * 64 + mt * 16 + g4;
                        int bb = row0 >> 11, nn = row0 & 2047;
                        union { unsigned short u[4]; uint2 v; } o;
                        #pragma unroll
                        for (int r = 0; r < 4; r++) o.u[r] = f2b(acc[mt][2 * p + j][r]);
                        *(uint2*)(vt + ((size_t)(bb * 2048 + d)) * 2048 + nn) = o.v;
                    }
                }
            }
        }
    }
}

// ---------------- output projection: 128x128 tile, BK=64, swizzled staging ----------------
__global__ __launch_bounds__(256) void gemm_out(const unsigned short* __restrict__ A,
                                                const unsigned short* __restrict__ Bw,
                                                float* __restrict__ Cf) {
    __shared__ unsigned short sA[128 * 64];
    __shared__ unsigned short sB[128 * 64];
    const int K = DMODEL, Nn = DMODEL;
    const int tid = threadIdx.x;
    const int wave = tid >> 6, lane = tid & 63;
    const int m0 = blockIdx.y * 128, n0 = blockIdx.x * 128;
    const int wm = (wave >> 1) * 64, wn = (wave & 1) * 64;

    f32x4 acc[4][4] = {};

    const int srowoff = wave * 8 + (lane >> 3);
    const int gchunk = ((lane & 7) ^ ((lane >> 3) & 7)) * 8;
    const unsigned short* Ag = A + (size_t)(m0 + srowoff) * K + gchunk;
    const unsigned short* Bg = Bw + (size_t)(n0 + srowoff) * K + gchunk;
    unsigned short* sAw = &sA[(wave * 8) * 64];
    unsigned short* sBw = &sB[(wave * 8) * 64];

    const int fr = lane & 15, grp = lane >> 4;
    const int swz = fr & 7;

    for (int kb = 0; kb < K; kb += 64) {
        #pragma unroll
        for (int i = 0; i < 4; i++)
            gld_lds16(Ag + (size_t)(i * 32) * K + kb, sAw + i * 32 * 64);
        #pragma unroll
        for (int i = 0; i < 4; i++)
            gld_lds16(Bg + (size_t)(i * 32) * K + kb, sBw + i * 32 * 64);
        __syncthreads();
        #pragma unroll
        for (int ks = 0; ks < 2; ks++) {
            bf16x8 af[4], bfr[4];
            #pragma unroll
            for (int mt = 0; mt < 4; mt++)
                af[mt] = *(const bf16x8*)&sA[(wm + mt * 16 + fr) * 64 + (((ks * 4 + grp) ^ swz) << 3)];
            #pragma unroll
            for (int nt = 0; nt < 4; nt++)
                bfr[nt] = *(const bf16x8*)&sB[(wn + nt * 16 + fr) * 64 + (((ks * 4 + grp) ^ swz) << 3)];
            #pragma unroll
            for (int mt = 0; mt < 4; mt++)
                #pragma unroll
                for (int nt = 0; nt < 4; nt++)
                    acc[mt][nt] = __builtin_amdgcn_mfma_f32_16x16x32_bf16(af[mt], bfr[nt], acc[mt][nt], 0, 0, 0);
        }
        __syncthreads();
    }

    const int g4 = (lane >> 4) * 4, c0 = lane & 15;
    #pragma unroll
    for (int mt = 0; mt < 4; mt++)
        #pragma unroll
        for (int nt = 0; nt < 4; nt++) {
            int col = n0 + wn + nt * 16 + c0;
            #pragma unroll
            for (int r = 0; r < 4; r++) {
                int row = m0 + wm + mt * 16 + g4 + r;
                Cf[(size_t)row * Nn + col] = acc[mt][nt][r];
            }
        }
}

// ---------------- Flash attention, S^T formulation (round-2 version, kept) ----------------
__global__ __launch_bounds__(256) void attn_kernel(const unsigned short* __restrict__ Q,
                                                   const unsigned short* __restrict__ Kg,
                                                   const unsigned short* __restrict__ Vt,
                                                   unsigned short* __restrict__ O) {
    __shared__ unsigned short sK[2][64 * 128];
    __shared__ unsigned short sV[2][128 * 64];

    const int lin = blockIdx.x;
    const int swz = (lin & 7) * 64 + (lin >> 3);   // bijective: 512 = 8*64
    const int qt = swz & 15;
    const int bh = swz >> 4;
    const int b = bh >> 4, h = bh & 15;
    const int tid = threadIdx.x, wave = tid >> 6, lane = tid & 63;
    const int c0 = lane & 15, grp = lane >> 4;

    bf16x8 qf[2][4];
    {
        const unsigned short* Qbase = Q + (size_t)(b * NSEQ + qt * 128 + wave * 32 + c0) * DMODEL + h * HD + grp * 8;
        #pragma unroll
        for (int nt = 0; nt < 2; nt++)
            #pragma unroll
            for (int ks = 0; ks < 4; ks++)
                qf[nt][ks] = *(const bf16x8*)(Qbase + (size_t)nt * 16 * DMODEL + ks * 32);
    }

    f32x4 oacc[8][2] = {};                    // O^T[d = mo*16+grp*4+r][q = nt*16+c0]
    float lsum[2] = {0.f, 0.f};

    const unsigned short* Kbase = Kg + (size_t)(b * NSEQ) * DMODEL + h * HD;
    const unsigned short* Vbase = Vt + (size_t)(bh * HD) * NSEQ;

    #define ATTN_STAGE(bi, kv0)                                                        \
        {                                                                              \
            _Pragma("unroll")                                                          \
            for (int i = 0; i < 4; i++) {                                              \
                int rr = wave * 16 + i * 4 + (lane >> 4);                              \
                int gc = ((lane & 15) ^ (rr & 15)) * 8;                                \
                gld_lds16(Kbase + (size_t)((kv0) + rr) * DMODEL + gc,                  \
                          &sK[bi][(wave * 16 + i * 4) * 128]);                         \
            }                                                                          \
            _Pragma("unroll")                                                          \
            for (int i = 0; i < 4; i++) {                                              \
                int rr = wave * 32 + i * 8 + (lane >> 3);                              \
                int gc = ((lane & 7) ^ (lane >> 3)) * 8;                               \
                gld_lds16(Vbase + (size_t)rr * NSEQ + (kv0) + gc,                      \
                          &sV[bi][(wave * 32 + i * 8) * 64]);                          \
            }                                                                          \
        }

    ATTN_STAGE(0, 0);
    __syncthreads();   // vmcnt(0) drain: tile 0 landed

    for (int it = 0; it < 32; it++) {
        const unsigned short* sKb = sK[it & 1];
        const unsigned short* sVb = sV[it & 1];

        if (it < 31) {
            ATTN_STAGE((it + 1) & 1, (it + 1) * 64);
        }
        __builtin_amdgcn_sched_barrier(0);   // keep stage issues ahead of compute

        f32x4 s[4][2] = {};
        #pragma unroll
        for (int ks = 0; ks < 4; ks++) {
            bf16x8 kf[4];
            #pragma unroll
            for (int mt = 0; mt < 4; mt++)
                kf[mt] = *(const bf16x8*)&sKb[(mt * 16 + c0) * 128 + (((ks * 4 + grp) ^ c0) << 3)];
            #pragma unroll
            for (int mt = 0; mt < 4; mt++)
                #pragma unroll
                for (int nt = 0; nt < 2; nt++)
                    s[mt][nt] = __builtin_amdgcn_mfma_f32_16x16x32_bf16(kf[mt], qf[nt][ks], s[mt][nt], 0, 0, 0);
        }

        bf16x4 pk[4][2];
        #pragma unroll
        for (int mt = 0; mt < 4; mt++)
            #pragma unroll
            for (int nt = 0; nt < 2; nt++) {
                float p0 = __expf(s[mt][nt][0]);
                float p1 = __expf(s[mt][nt][1]);
                float p2 = __expf(s[mt][nt][2]);
                float p3 = __expf(s[mt][nt][3]);
                lsum[nt] += (p0 + p1) + (p2 + p3);
                bf16x4 t;
                t[0] = (short)f2b(p0); t[1] = (short)f2b(p1);
                t[2] = (short)f2b(p2); t[3] = (short)f2b(p3);
                pk[mt][nt] = t;
            }

        #pragma unroll
        for (int mtK = 0; mtK < 4; mtK++) {
            bf16x4 va[8];
            #pragma unroll
            for (int mo = 0; mo < 8; mo++)
                va[mo] = *(const bf16x4*)&sVb[(mo * 16 + c0) * 64
                                              + (((mtK * 2 + (grp >> 1)) ^ (c0 & 7)) << 3)
                                              + (grp & 1) * 4];
            #pragma unroll
            for (int mo = 0; mo < 8; mo++)
                #pragma unroll
                for (int nt = 0; nt < 2; nt++)
                    oacc[mo][nt] = __builtin_amdgcn_mfma_f32_16x16x16bf16_1k(va[mo], pk[mtK][nt], oacc[mo][nt], 0, 0, 0);
        }

        __syncthreads();   // vmcnt(0): stage(it+1) landed
    }
    #undef ATTN_STAGE

    float invl[2];
    #pragma unroll
    for (int nt = 0; nt < 2; nt++) {
        float li = lsum[nt];
        li += __shfl_xor(li, 16);
        li += __shfl_xor(li, 32);
        invl[nt] = 1.0f / li;
    }
    #pragma unroll
    for (int mo = 0; mo < 8; mo++)
        #pragma unroll
        for (int nt = 0; nt < 2; nt++) {
            union { unsigned short u[4]; uint2 v; } o;
            #pragma unroll
            for (int r = 0; r < 4; r++)
                o.u[r] = f2b(oacc[mo][nt][r] * invl[nt]);
            int row = b * NSEQ + qt * 128 + wave * 32 + nt * 16 + c0;
            int col = h * HD + mo * 16 + grp * 4;
            *(uint2*)(O + (size_t)row * DMODEL + col) = o.v;
        }
}

extern "C" void kernel_launch(void* const* d_in, const int* in_sizes, int n_in,
                              void* d_out, int out_size, void* d_ws, size_t ws_size,
                              hipStream_t stream) {
    const float* x  = (const float*)d_in[0];
    const float* Wq = (const float*)d_in[1];
    const float* Wk = (const float*)d_in[2];
    const float* Wv = (const float*)d_in[3];
    const float* Wo = (const float*)d_in[4];

    char* ws = (char*)d_ws;
    // xb(16M, reused as attn O) | wqb..wob (4x8M contiguous) | qb(16M)+kb(16M) contiguous | vt(16M)
    unsigned short* xb  = (unsigned short*)(ws);
    unsigned short* wqb = (unsigned short*)(ws + 16777216);
    unsigned short* wob = (unsigned short*)(ws + 16777216 + 3 * 8388608);
    unsigned short* qb  = (unsigned short*)(ws + 50331648);
    unsigned short* kb  = (unsigned short*)(ws + 67108864);
    unsigned short* vt  = (unsigned short*)(ws + 83886080);

    cast_all_kernel<<<12288, 256, 0, stream>>>(x, Wq, Wk, Wv, Wo, xb, wqb);

    gemm_qkv<<<512, 512, 0, stream>>>(xb, wqb, qb, vt);

    attn_kernel<<<512, 256, 0, stream>>>(qb, kb, vt, xb);

    gemm_out<<<dim3(16, 32), 256, 0, stream>>>(xb, wob, (float*)d_out);
}

// Round 4
// 393.959 us; speedup vs baseline: 1.0350x; 1.0350x over previous
//
#include <hip/hip_runtime.h>
#include <hip/hip_bf16.h>
#include <math.h>

typedef short bf16x8 __attribute__((ext_vector_type(8)));
typedef short bf16x4 __attribute__((ext_vector_type(4)));
typedef float f32x4 __attribute__((ext_vector_type(4)));

#define NSEQ 2048
#define DMODEL 2048
#define NH 16
#define HD 128
#define BATCH 2
#define MROWS 4096  // BATCH*NSEQ

__device__ __forceinline__ unsigned short f2b(float f) {
    __hip_bfloat16 h = __float2bfloat16(f);
    return *reinterpret_cast<unsigned short*>(&h);
}
__device__ __forceinline__ float b2f(unsigned short u) {
    __hip_bfloat16 h;
    *reinterpret_cast<unsigned short*>(&h) = u;
    return __bfloat162float(h);
}

__device__ __forceinline__ void gld_lds16(const unsigned short* g, unsigned short* l) {
    __builtin_amdgcn_global_load_lds(
        (const __attribute__((address_space(1))) unsigned int*)(const void*)g,
        (__attribute__((address_space(3))) unsigned int*)(void*)l,
        16, 0, 0);
}

// ---------------- fused cast fp32 -> bf16 for x + 4 weights (HBM-roofline) ----------------
__global__ __launch_bounds__(256) void cast_all_kernel(const float* __restrict__ x,
                                                       const float* __restrict__ wq,
                                                       const float* __restrict__ wk,
                                                       const float* __restrict__ wv,
                                                       const float* __restrict__ wo,
                                                       unsigned short* __restrict__ xb,
                                                       unsigned short* __restrict__ wqb) {
    int bid = blockIdx.x;
    const float* src;
    unsigned short* dst;
    int off;
    if (bid < 4096) {
        src = x; dst = xb; off = bid;
    } else {
        int w = (bid - 4096) >> 11;
        src = (w == 0) ? wq : (w == 1) ? wk : (w == 2) ? wv : wo;
        dst = wqb + (size_t)w * 4194304;
        off = (bid - 4096) & 2047;
    }
    int i = (off * 256 + threadIdx.x) * 8;
    float4 a = *(const float4*)(src + i);
    float4 b = *(const float4*)(src + i + 4);
    union { unsigned short u[8]; uint4 v; } tmp;
    tmp.u[0] = f2b(a.x); tmp.u[1] = f2b(a.y); tmp.u[2] = f2b(a.z); tmp.u[3] = f2b(a.w);
    tmp.u[4] = f2b(b.x); tmp.u[5] = f2b(b.y); tmp.u[6] = f2b(b.z); tmp.u[7] = f2b(b.w);
    *(uint4*)(dst + i) = tmp.v;
}

// ---------------- QKV GEMM + fused RoPE: 128x256 tile, K=32 ring (depth 3), 2 blocks/CU ----
// Round-4 theory: pipelined schedule (counted vmcnt, raw s_barrier) AND high occupancy.
// 72 KB LDS -> 2 blocks/CU -> 16 waves/CU (4/SIMD): cross-block wave overlap (m114)
// covers barrier/lgkm stalls, ring prefetch (steady vmcnt(3), never 0) removes the
// barrier drain. Grid 768 = exactly 3 blocks/CU, XCD-chunked m-fastest (B-panels L2-fit).
// acc[4][4]=64 VGPR; __launch_bounds__(512,4) targets <=128 VGPR (16-wave threshold).
// Both-sides chunk XOR swizzle (0 conflicts measured r1/r3). Wave n-cols stride 64 so
// RoPE (d,d+64) pairs are wave-local; 256-wide n-tiles never straddle Q/K/V boundaries.
__global__ __launch_bounds__(512, 4) void gemm_qkv(const unsigned short* __restrict__ A,
                                                   const unsigned short* __restrict__ Bw,
                                                   unsigned short* __restrict__ qk,
                                                   unsigned short* __restrict__ vt) {
    __shared__ unsigned short sA[3][128 * 32];
    __shared__ unsigned short sB[3][256 * 32];
    const int K = DMODEL;
    const int tid = threadIdx.x;
    const int wave = tid >> 6, lane = tid & 63;

    const int bid = blockIdx.x;
    const int xcd = bid & 7, idx = bid >> 3;        // 96 tiles per XCD
    const int m0 = (idx & 31) * 128;                // m-fastest
    const int n0 = (xcd * 3 + (idx >> 5)) * 256;    // 3 n-columns per XCD

    const int wr = wave >> 2, wc = wave & 3;
    const int fr = lane & 15, grp = lane >> 4;
    const int rsw = (grp ^ ((fr >> 1) & 3)) << 3;   // swizzled k-chunk for ds_read

    // staging sweep: wave covers rows base + wave*16 + (lane>>2), LDS chunk lane&3,
    // fetched global chunk = (lane&3) ^ ((row>>1)&3) == (lane&3) ^ ((lane>>3)&3).
    const int sr = wave * 16 + (lane >> 2);
    const int sc = (((lane & 3) ^ ((lane >> 3) & 3)) << 3);
    const unsigned short* Ag = A + (size_t)(m0 + sr) * K + sc;
    const unsigned short* Bg = Bw + (size_t)(n0 + sr) * K + sc;

    f32x4 acc[4][4] = {};

    // one slice = 3 vmem ops/thread: 1 A-sweep (128 rows) + 2 B-sweeps (256 rows)
    #define QKV_STAGE(sl, t)                                                             \
        {                                                                                \
            gld_lds16(Ag + (t) * 32, &sA[sl][(wave * 16) * 32]);                         \
            gld_lds16(Bg + (t) * 32, &sB[sl][(wave * 16) * 32]);                         \
            gld_lds16(Bg + (size_t)128 * K + (t) * 32, &sB[sl][(128 + wave * 16) * 32]); \
        }

    // prologue: stage slices 0,1; wait slice 0 (oldest 3 of 6) -> vmcnt(3)
    QKV_STAGE(0, 0);
    QKV_STAGE(1, 1);
    __builtin_amdgcn_sched_barrier(0);
    asm volatile("s_waitcnt vmcnt(3)" ::: "memory");
    asm volatile("s_barrier" ::: "memory");

    const int aoff = (wr * 64 + fr) * 32 + rsw;     // + mt*512
    const int boff = (wc * 16 + fr) * 32 + rsw;     // + nt*2048 (n-cols stride 64 rows)

    int slot = 0;
    for (int s = 0; s < 64; s++) {
        // stage slice s+2 into slot (s+2)%3 (vacated at the s-1 barrier)
        if (s < 62) {
            int sl = slot + 2; if (sl >= 3) sl -= 3;
            QKV_STAGE(sl, s + 2);
        }
        bf16x8 af[4], bfr[4];
        #pragma unroll
        for (int mt = 0; mt < 4; mt++)
            af[mt] = *(const bf16x8*)&sA[slot][aoff + mt * 512];
        #pragma unroll
        for (int nt = 0; nt < 4; nt++)
            bfr[nt] = *(const bf16x8*)&sB[slot][boff + nt * 2048];
        __builtin_amdgcn_sched_barrier(0);
        asm volatile("s_waitcnt lgkmcnt(0)" ::: "memory");
        __builtin_amdgcn_sched_barrier(0);
        __builtin_amdgcn_s_setprio(1);
        #pragma unroll
        for (int mt = 0; mt < 4; mt++)
            #pragma unroll
            for (int nt = 0; nt < 4; nt++)
                acc[mt][nt] = __builtin_amdgcn_mfma_f32_16x16x32_bf16(af[mt], bfr[nt], acc[mt][nt], 0, 0, 0);
        __builtin_amdgcn_s_setprio(0);
        __builtin_amdgcn_sched_barrier(0);
        // counted drain: slice s+1's 3 loads landed; never 0 until tail.
        if (s < 62)       { asm volatile("s_waitcnt vmcnt(3)" ::: "memory"); }
        else if (s == 62) { asm volatile("s_waitcnt vmcnt(0)" ::: "memory"); }
        asm volatile("s_barrier" ::: "memory");
        slot++; if (slot >= 3) slot -= 3;
    }
    #undef QKV_STAGE

    // ---------- epilogue ----------
    // acc[mt][nt][r]: row = m0 + wr*64 + mt*16 + grp*4 + r
    //                 col = n0 + nt*64 + wc*16 + c0   (nt pairs (0,1),(2,3) = RoPE lo/hi)
    const int c0 = fr;
    if (n0 < 4096) {
        const int region = n0 >> 11;                 // 0=Q, 1=K (256-tiles never straddle)
        const float scale = (region == 0) ? 0.08838834764831845f : 1.0f;
        unsigned short* dst = qk + (size_t)region * 8388608 + ((n0 & 2047) + wc * 16 + c0);
        const float inv = exp2f((float)(wc * 16 + c0) * -0.2076205059304545f);  // 10000^(-d/64)
        #pragma unroll
        for (int mt = 0; mt < 4; mt++) {
            #pragma unroll
            for (int r = 0; r < 4; r++) {
                int row = m0 + wr * 64 + mt * 16 + grp * 4 + r;
                float nf = (float)(row & (NSEQ - 1));
                float sv, cv;
                __sincosf(nf * inv, &sv, &cv);
                size_t rb = (size_t)row * 2048;
                #pragma unroll
                for (int p = 0; p < 2; p++) {
                    float lo = acc[mt][2 * p][r], hi = acc[mt][2 * p + 1][r];
                    dst[rb + p * 128]      = f2b((lo * cv - hi * sv) * scale);
                    dst[rb + p * 128 + 64] = f2b((hi * cv + lo * sv) * scale);
                }
            }
        }
    } else {
        // V region: store transposed [b][d][seq], uint2 over 4 seq rows.
        #pragma unroll
        for (int nt = 0; nt < 4; nt++) {
            int d = n0 - 4096 + nt * 64 + wc * 16 + c0;
            #pragma unroll
            for (int mt = 0; mt < 4; mt++) {
                int row0 = m0 + wr * 64 + mt * 16 + grp * 4;
                int bb = row0 >> 11, nn = row0 & 2047;
                union { unsigned short u[4]; uint2 v; } o;
                #pragma unroll
                for (int r = 0; r < 4; r++) o.u[r] = f2b(acc[mt][nt][r]);
                *(uint2*)(vt + ((size_t)(bb * 2048 + d)) * 2048 + nn) = o.v;
            }
        }
    }
}

// ---------------- output projection: 128x128 tile, BK=64, swizzled staging ----------------
__global__ __launch_bounds__(256) void gemm_out(const unsigned short* __restrict__ A,
                                                const unsigned short* __restrict__ Bw,
                                                float* __restrict__ Cf) {
    __shared__ unsigned short sA[128 * 64];
    __shared__ unsigned short sB[128 * 64];
    const int K = DMODEL, Nn = DMODEL;
    const int tid = threadIdx.x;
    const int wave = tid >> 6, lane = tid & 63;
    const int m0 = blockIdx.y * 128, n0 = blockIdx.x * 128;
    const int wm = (wave >> 1) * 64, wn = (wave & 1) * 64;

    f32x4 acc[4][4] = {};

    const int srowoff = wave * 8 + (lane >> 3);
    const int gchunk = ((lane & 7) ^ ((lane >> 3) & 7)) * 8;
    const unsigned short* Ag = A + (size_t)(m0 + srowoff) * K + gchunk;
    const unsigned short* Bg = Bw + (size_t)(n0 + srowoff) * K + gchunk;
    unsigned short* sAw = &sA[(wave * 8) * 64];
    unsigned short* sBw = &sB[(wave * 8) * 64];

    const int fr = lane & 15, grp = lane >> 4;
    const int swz = fr & 7;

    for (int kb = 0; kb < K; kb += 64) {
        #pragma unroll
        for (int i = 0; i < 4; i++)
            gld_lds16(Ag + (size_t)(i * 32) * K + kb, sAw + i * 32 * 64);
        #pragma unroll
        for (int i = 0; i < 4; i++)
            gld_lds16(Bg + (size_t)(i * 32) * K + kb, sBw + i * 32 * 64);
        __syncthreads();
        #pragma unroll
        for (int ks = 0; ks < 2; ks++) {
            bf16x8 af[4], bfr[4];
            #pragma unroll
            for (int mt = 0; mt < 4; mt++)
                af[mt] = *(const bf16x8*)&sA[(wm + mt * 16 + fr) * 64 + (((ks * 4 + grp) ^ swz) << 3)];
            #pragma unroll
            for (int nt = 0; nt < 4; nt++)
                bfr[nt] = *(const bf16x8*)&sB[(wn + nt * 16 + fr) * 64 + (((ks * 4 + grp) ^ swz) << 3)];
            #pragma unroll
            for (int mt = 0; mt < 4; mt++)
                #pragma unroll
                for (int nt = 0; nt < 4; nt++)
                    acc[mt][nt] = __builtin_amdgcn_mfma_f32_16x16x32_bf16(af[mt], bfr[nt], acc[mt][nt], 0, 0, 0);
        }
        __syncthreads();
    }

    const int g4 = (lane >> 4) * 4, c0 = lane & 15;
    #pragma unroll
    for (int mt = 0; mt < 4; mt++)
        #pragma unroll
        for (int nt = 0; nt < 4; nt++) {
            int col = n0 + wn + nt * 16 + c0;
            #pragma unroll
            for (int r = 0; r < 4; r++) {
                int row = m0 + wm + mt * 16 + g4 + r;
                Cf[(size_t)row * Nn + col] = acc[mt][nt][r];
            }
        }
}

// ---------------- Flash attention, S^T formulation (round-2 version, kept) ----------------
__global__ __launch_bounds__(256) void attn_kernel(const unsigned short* __restrict__ Q,
                                                   const unsigned short* __restrict__ Kg,
                                                   const unsigned short* __restrict__ Vt,
                                                   unsigned short* __restrict__ O) {
    __shared__ unsigned short sK[2][64 * 128];
    __shared__ unsigned short sV[2][128 * 64];

    const int lin = blockIdx.x;
    const int swz = (lin & 7) * 64 + (lin >> 3);   // bijective: 512 = 8*64
    const int qt = swz & 15;
    const int bh = swz >> 4;
    const int b = bh >> 4, h = bh & 15;
    const int tid = threadIdx.x, wave = tid >> 6, lane = tid & 63;
    const int c0 = lane & 15, grp = lane >> 4;

    bf16x8 qf[2][4];
    {
        const unsigned short* Qbase = Q + (size_t)(b * NSEQ + qt * 128 + wave * 32 + c0) * DMODEL + h * HD + grp * 8;
        #pragma unroll
        for (int nt = 0; nt < 2; nt++)
            #pragma unroll
            for (int ks = 0; ks < 4; ks++)
                qf[nt][ks] = *(const bf16x8*)(Qbase + (size_t)nt * 16 * DMODEL + ks * 32);
    }

    f32x4 oacc[8][2] = {};                    // O^T[d = mo*16+grp*4+r][q = nt*16+c0]
    float lsum[2] = {0.f, 0.f};

    const unsigned short* Kbase = Kg + (size_t)(b * NSEQ) * DMODEL + h * HD;
    const unsigned short* Vbase = Vt + (size_t)(bh * HD) * NSEQ;

    #define ATTN_STAGE(bi, kv0)                                                        \
        {                                                                              \
            _Pragma("unroll")                                                          \
            for (int i = 0; i < 4; i++) {                                              \
                int rr = wave * 16 + i * 4 + (lane >> 4);                              \
                int gc = ((lane & 15) ^ (rr & 15)) * 8;                                \
                gld_lds16(Kbase + (size_t)((kv0) + rr) * DMODEL + gc,                  \
                          &sK[bi][(wave * 16 + i * 4) * 128]);                         \
            }                                                                          \
            _Pragma("unroll")                                                          \
            for (int i = 0; i < 4; i++) {                                              \
                int rr = wave * 32 + i * 8 + (lane >> 3);                              \
                int gc = ((lane & 7) ^ (lane >> 3)) * 8;                               \
                gld_lds16(Vbase + (size_t)rr * NSEQ + (kv0) + gc,                      \
                          &sV[bi][(wave * 32 + i * 8) * 64]);                          \
            }                                                                          \
        }

    ATTN_STAGE(0, 0);
    __syncthreads();   // vmcnt(0) drain: tile 0 landed

    for (int it = 0; it < 32; it++) {
        const unsigned short* sKb = sK[it & 1];
        const unsigned short* sVb = sV[it & 1];

        if (it < 31) {
            ATTN_STAGE((it + 1) & 1, (it + 1) * 64);
        }
        __builtin_amdgcn_sched_barrier(0);   // keep stage issues ahead of compute

        f32x4 s[4][2] = {};
        #pragma unroll
        for (int ks = 0; ks < 4; ks++) {
            bf16x8 kf[4];
            #pragma unroll
            for (int mt = 0; mt < 4; mt++)
                kf[mt] = *(const bf16x8*)&sKb[(mt * 16 + c0) * 128 + (((ks * 4 + grp) ^ c0) << 3)];
            #pragma unroll
            for (int mt = 0; mt < 4; mt++)
                #pragma unroll
                for (int nt = 0; nt < 2; nt++)
                    s[mt][nt] = __builtin_amdgcn_mfma_f32_16x16x32_bf16(kf[mt], qf[nt][ks], s[mt][nt], 0, 0, 0);
        }

        bf16x4 pk[4][2];
        #pragma unroll
        for (int mt = 0; mt < 4; mt++)
            #pragma unroll
            for (int nt = 0; nt < 2; nt++) {
                float p0 = __expf(s[mt][nt][0]);
                float p1 = __expf(s[mt][nt][1]);
                float p2 = __expf(s[mt][nt][2]);
                float p3 = __expf(s[mt][nt][3]);
                lsum[nt] += (p0 + p1) + (p2 + p3);
                bf16x4 t;
                t[0] = (short)f2b(p0); t[1] = (short)f2b(p1);
                t[2] = (short)f2b(p2); t[3] = (short)f2b(p3);
                pk[mt][nt] = t;
            }

        #pragma unroll
        for (int mtK = 0; mtK < 4; mtK++) {
            bf16x4 va[8];
            #pragma unroll
            for (int mo = 0; mo < 8; mo++)
                va[mo] = *(const bf16x4*)&sVb[(mo * 16 + c0) * 64
                                              + (((mtK * 2 + (grp >> 1)) ^ (c0 & 7)) << 3)
                                              + (grp & 1) * 4];
            #pragma unroll
            for (int mo = 0; mo < 8; mo++)
                #pragma unroll
                for (int nt = 0; nt < 2; nt++)
                    oacc[mo][nt] = __builtin_amdgcn_mfma_f32_16x16x16bf16_1k(va[mo], pk[mtK][nt], oacc[mo][nt], 0, 0, 0);
        }

        __syncthreads();   // vmcnt(0): stage(it+1) landed
    }
    #undef ATTN_STAGE

    float invl[2];
    #pragma unroll
    for (int nt = 0; nt < 2; nt++) {
        float li = lsum[nt];
        li += __shfl_xor(li, 16);
        li += __shfl_xor(li, 32);
        invl[nt] = 1.0f / li;
    }
    #pragma unroll
    for (int mo = 0; mo < 8; mo++)
        #pragma unroll
        for (int nt = 0; nt < 2; nt++) {
            union { unsigned short u[4]; uint2 v; } o;
            #pragma unroll
            for (int r = 0; r < 4; r++)
                o.u[r] = f2b(oacc[mo][nt][r] * invl[nt]);
            int row = b * NSEQ + qt * 128 + wave * 32 + nt * 16 + c0;
            int col = h * HD + mo * 16 + grp * 4;
            *(uint2*)(O + (size_t)row * DMODEL + col) = o.v;
        }
}

extern "C" void kernel_launch(void* const* d_in, const int* in_sizes, int n_in,
                              void* d_out, int out_size, void* d_ws, size_t ws_size,
                              hipStream_t stream) {
    const float* x  = (const float*)d_in[0];
    const float* Wq = (const float*)d_in[1];
    const float* Wk = (const float*)d_in[2];
    const float* Wv = (const float*)d_in[3];
    const float* Wo = (const float*)d_in[4];

    char* ws = (char*)d_ws;
    // xb(16M, reused as attn O) | wqb..wob (4x8M contiguous) | qb(16M)+kb(16M) contiguous | vt(16M)
    unsigned short* xb  = (unsigned short*)(ws);
    unsigned short* wqb = (unsigned short*)(ws + 16777216);
    unsigned short* wob = (unsigned short*)(ws + 16777216 + 3 * 8388608);
    unsigned short* qb  = (unsigned short*)(ws + 50331648);
    unsigned short* kb  = (unsigned short*)(ws + 67108864);
    unsigned short* vt  = (unsigned short*)(ws + 83886080);

    cast_all_kernel<<<12288, 256, 0, stream>>>(x, Wq, Wk, Wv, Wo, xb, wqb);

    gemm_qkv<<<768, 512, 0, stream>>>(xb, wqb, qb, vt);

    attn_kernel<<<512, 256, 0, stream>>>(qb, kb, vt, xb);

    gemm_out<<<dim3(16, 32), 256, 0, stream>>>(xb, wob, (float*)d_out);
}